// Round 2
// baseline (8941.013 us; speedup 1.0000x reference)
//
#include <hip/hip_runtime.h>

#define NNODES 100000
#define NEDGES 600000
#define NGRAPH 64
#define HID 128
#define RHD 500
#define BM 128
#define BK 64

__device__ __forceinline__ float leaky1(float x) { return x >= 0.0f ? x : 0.01f * x; }

// ---------------- layer 0: edge message (d=2) ----------------
__global__ __launch_bounds__(256) void edge0_kernel(
    const float* __restrict__ x, const int* __restrict__ ei,
    const float* __restrict__ ea, const float* __restrict__ ew,
    const float* __restrict__ eb, float* __restrict__ aggr)
{
    int e = blockIdx.x * 256 + threadIdx.x;
    if (e >= NEDGES) return;
    int s = ei[e];
    int d = ei[NEDGES + e];
    float a[7];
#pragma unroll
    for (int k = 0; k < 7; ++k) a[k] = ea[e * 7 + k];
    float e0 = eb[0], e1 = eb[1];
#pragma unroll
    for (int k = 0; k < 7; ++k) { e0 = fmaf(a[k], ew[k], e0); e1 = fmaf(a[k], ew[7 + k], e1); }
    float m0 = fmaxf(x[s * 2 + 0] + e0, 0.0f);
    float m1 = fmaxf(x[s * 2 + 1] + e1, 0.0f);
    atomicAdd(&aggr[d * 2 + 0], m0);
    atomicAdd(&aggr[d * 2 + 1], m1);
}

// ---------------- hidden layers: edge message (d=128), one wave per edge ----------------
__global__ __launch_bounds__(256) void edge_kernel(
    const float* __restrict__ xin, const int* __restrict__ ei,
    const float* __restrict__ ea, const float* __restrict__ ew,
    const float* __restrict__ eb, float* __restrict__ aggr)
{
    int lane = threadIdx.x & 63;
    int e = blockIdx.x * 4 + (threadIdx.x >> 6);
    int s = ei[e];
    int d = ei[NEDGES + e];
    float a[7];
#pragma unroll
    for (int k = 0; k < 7; ++k) a[k] = ea[e * 7 + k];
    int j0 = lane, j1 = lane + 64;
    float acc0 = eb[j0], acc1 = eb[j1];
#pragma unroll
    for (int k = 0; k < 7; ++k) {
        acc0 = fmaf(a[k], ew[j0 * 7 + k], acc0);
        acc1 = fmaf(a[k], ew[j1 * 7 + k], acc1);
    }
    float m0 = fmaxf(xin[s * HID + j0] + acc0, 0.0f);
    float m1 = fmaxf(xin[s * HID + j1] + acc1, 0.0f);
    atomicAdd(&aggr[d * HID + j0], m0);
    atomicAdd(&aggr[d * HID + j1], m1);
}

// ---------------- layer 0: GEMM1 (in=2 -> 128) ----------------
__global__ __launch_bounds__(256) void gemm1_l0_kernel(
    const float* __restrict__ x, const float* __restrict__ aggr,
    const float* __restrict__ w1, const float* __restrict__ b1,
    float* __restrict__ h1)
{
    int n = blockIdx.x * 256 + threadIdx.x;
    if (n >= NNODES) return;
    float x0 = x[n * 2 + 0] + aggr[n * 2 + 0];
    float x1 = x[n * 2 + 1] + aggr[n * 2 + 1];
    float4* out4 = (float4*)(h1 + (size_t)n * HID);
    for (int j = 0; j < HID; j += 4) {
        float4 o;
        o.x = fmaf(x1, w1[(j + 0) * 2 + 1], fmaf(x0, w1[(j + 0) * 2 + 0], b1[j + 0]));
        o.y = fmaf(x1, w1[(j + 1) * 2 + 1], fmaf(x0, w1[(j + 1) * 2 + 0], b1[j + 1]));
        o.z = fmaf(x1, w1[(j + 2) * 2 + 1], fmaf(x0, w1[(j + 2) * 2 + 0], b1[j + 2]));
        o.w = fmaf(x1, w1[(j + 3) * 2 + 1], fmaf(x0, w1[(j + 3) * 2 + 0], b1[j + 3]));
        out4[j >> 2] = o;
    }
}

// ---------------- BN statistics (layer 0 only) ----------------
__global__ __launch_bounds__(256) void bn_stats_kernel(
    const float* __restrict__ h1, float* __restrict__ acc)
{
    __shared__ float ls[HID], lq[HID];
    int c = threadIdx.x & 127;
    int half = threadIdx.x >> 7;
    int base = blockIdx.x * 256;
    int end = base + 256; if (end > NNODES) end = NNODES;
    float s = 0.0f, q = 0.0f;
    for (int r = base + half; r < end; r += 2) {
        float v = h1[(size_t)r * HID + c];
        s += v;
        q = fmaf(v, v, q);
    }
    if (half) { ls[c] = s; lq[c] = q; }
    __syncthreads();
    if (!half) {
        s += ls[c]; q += lq[c];
        atomicAdd(&acc[c], s);
        atomicAdd(&acc[HID + c], q);
    }
}

// ---------------- tiled GEMM1: h1 = (x+aggr)@W1^T + b1, fused BN stats ----------------
// 256 thr, tile 128x128, thread tile 8x8. A in LDS (xor-swizzled), B(weights) via L1.
__global__ __launch_bounds__(256) void gemm1_tiled(
    const float* __restrict__ xin, const float* __restrict__ aggr,
    const float* __restrict__ w1, const float* __restrict__ b1,
    float* __restrict__ h1, float* __restrict__ bn)
{
    __shared__ float4 sA[BM * 16];   // 32KB, float4-swizzled
    const int t = threadIdx.x;
    const int m_base = blockIdx.x * BM;
    const int tm = t >> 4, tn = t & 15;
    const int m0 = tm * 8, n0 = tn * 8;
    const int swz = tm & 7;

    float acc[8][8];
#pragma unroll
    for (int i = 0; i < 8; ++i)
#pragma unroll
        for (int j = 0; j < 8; ++j) acc[i][j] = 0.0f;

    const int sr = t >> 1;           // staging row 0..127
    const int sc4 = (t & 1) * 8;     // staging col4 base
    const int swz_s = (sr >> 3) & 7;

    for (int k0 = 0; k0 < HID; k0 += BK) {
        __syncthreads();
        {
            int gm = m_base + sr;
            float4* dst = sA + sr * 16;
            if (gm < NNODES) {
                const float4* xp = (const float4*)(xin + (size_t)gm * HID + k0) + sc4;
                const float4* ap = (const float4*)(aggr + (size_t)gm * HID + k0) + sc4;
#pragma unroll
                for (int u = 0; u < 8; ++u) {
                    float4 a = xp[u], g = ap[u];
                    dst[(sc4 + u) ^ swz_s] = make_float4(a.x + g.x, a.y + g.y, a.z + g.z, a.w + g.w);
                }
            } else {
                float4 z = make_float4(0.f, 0.f, 0.f, 0.f);
#pragma unroll
                for (int u = 0; u < 8; ++u) dst[(sc4 + u) ^ swz_s] = z;
            }
        }
        __syncthreads();
        const float4* wp = (const float4*)(w1 + (size_t)n0 * HID + k0);
#pragma unroll 4
        for (int kk = 0; kk < 16; ++kk) {
            float4 b[8];
#pragma unroll
            for (int j = 0; j < 8; ++j) b[j] = wp[(size_t)j * 32 + kk];
            float4 a[8];
#pragma unroll
            for (int i = 0; i < 8; ++i) a[i] = sA[(m0 + i) * 16 + (kk ^ swz)];
#pragma unroll
            for (int i = 0; i < 8; ++i)
#pragma unroll
                for (int j = 0; j < 8; ++j) {
                    acc[i][j] = fmaf(a[i].x, b[j].x, acc[i][j]);
                    acc[i][j] = fmaf(a[i].y, b[j].y, acc[i][j]);
                    acc[i][j] = fmaf(a[i].z, b[j].z, acc[i][j]);
                    acc[i][j] = fmaf(a[i].w, b[j].w, acc[i][j]);
                }
        }
    }

    // epilogue: +bias, store, fused BN partial stats
    float bj[8];
#pragma unroll
    for (int j = 0; j < 8; ++j) bj[j] = b1[n0 + j];
    float s[8], q[8];
#pragma unroll
    for (int j = 0; j < 8; ++j) { s[j] = 0.0f; q[j] = 0.0f; }
#pragma unroll
    for (int i = 0; i < 8; ++i) {
        int gm = m_base + m0 + i;
        if (gm < NNODES) {
            float o[8];
#pragma unroll
            for (int j = 0; j < 8; ++j) {
                float v = acc[i][j] + bj[j];
                o[j] = v;
                s[j] += v;
                q[j] = fmaf(v, v, q[j]);
            }
            float4* op = (float4*)(h1 + (size_t)gm * HID + n0);
            op[0] = make_float4(o[0], o[1], o[2], o[3]);
            op[1] = make_float4(o[4], o[5], o[6], o[7]);
        }
    }
#pragma unroll
    for (int j = 0; j < 8; ++j) {
        atomicAdd(&bn[n0 + j], s[j]);
        atomicAdd(&bn[HID + n0 + j], q[j]);
    }
}

// ---------------- tiled GEMM2: hout = leaky(leaky( leaky(BN(h1)) @ W2^T + b2 )) ----------------
__global__ __launch_bounds__(256) void gemm2_tiled(
    const float* __restrict__ h1, const float* __restrict__ bnacc,
    const float* __restrict__ gamma, const float* __restrict__ beta,
    const float* __restrict__ w2, const float* __restrict__ b2,
    float* __restrict__ hout, float* __restrict__ aggr, int zero_aggr)
{
    __shared__ float4 sA[BM * 16];
    __shared__ float scv[HID], shv[HID];
    const int t = threadIdx.x;
    const int m_base = blockIdx.x * BM;
    const int tm = t >> 4, tn = t & 15;
    const int m0 = tm * 8, n0 = tn * 8;
    const int swz = tm & 7;

    if (t < HID) {
        const float invN = 1.0f / (float)NNODES;
        float su = bnacc[t], qu = bnacc[HID + t];
        float mu = su * invN;
        float var = fmaf(-mu, mu, qu * invN);
        float iv = rsqrtf(var + 1e-5f);
        float g = gamma[t] * iv;
        scv[t] = g;
        shv[t] = beta[t] - mu * g;
    }

    float acc[8][8];
#pragma unroll
    for (int i = 0; i < 8; ++i)
#pragma unroll
        for (int j = 0; j < 8; ++j) acc[i][j] = 0.0f;

    const int sr = t >> 1;
    const int sc4 = (t & 1) * 8;
    const int swz_s = (sr >> 3) & 7;

    for (int k0 = 0; k0 < HID; k0 += BK) {
        __syncthreads();   // also covers scv/shv on first iteration
        {
            int gm = m_base + sr;
            float4* dst = sA + sr * 16;
            if (gm < NNODES) {
                const float4* xp = (const float4*)(h1 + (size_t)gm * HID + k0) + sc4;
                const float4* scp = (const float4*)(scv + k0) + sc4;
                const float4* shp = (const float4*)(shv + k0) + sc4;
#pragma unroll
                for (int u = 0; u < 8; ++u) {
                    float4 v = xp[u], c = scp[u], h = shp[u];
                    float4 o;
                    o.x = leaky1(fmaf(v.x, c.x, h.x));
                    o.y = leaky1(fmaf(v.y, c.y, h.y));
                    o.z = leaky1(fmaf(v.z, c.z, h.z));
                    o.w = leaky1(fmaf(v.w, c.w, h.w));
                    dst[(sc4 + u) ^ swz_s] = o;
                }
            } else {
                float4 z = make_float4(0.f, 0.f, 0.f, 0.f);
#pragma unroll
                for (int u = 0; u < 8; ++u) dst[(sc4 + u) ^ swz_s] = z;
            }
        }
        __syncthreads();
        const float4* wp = (const float4*)(w2 + (size_t)n0 * HID + k0);
#pragma unroll 4
        for (int kk = 0; kk < 16; ++kk) {
            float4 b[8];
#pragma unroll
            for (int j = 0; j < 8; ++j) b[j] = wp[(size_t)j * 32 + kk];
            float4 a[8];
#pragma unroll
            for (int i = 0; i < 8; ++i) a[i] = sA[(m0 + i) * 16 + (kk ^ swz)];
#pragma unroll
            for (int i = 0; i < 8; ++i)
#pragma unroll
                for (int j = 0; j < 8; ++j) {
                    acc[i][j] = fmaf(a[i].x, b[j].x, acc[i][j]);
                    acc[i][j] = fmaf(a[i].y, b[j].y, acc[i][j]);
                    acc[i][j] = fmaf(a[i].z, b[j].z, acc[i][j]);
                    acc[i][j] = fmaf(a[i].w, b[j].w, acc[i][j]);
                }
        }
    }

    float bj[8];
#pragma unroll
    for (int j = 0; j < 8; ++j) bj[j] = b2[n0 + j];
    float4 z = make_float4(0.f, 0.f, 0.f, 0.f);
#pragma unroll
    for (int i = 0; i < 8; ++i) {
        int gm = m_base + m0 + i;
        if (gm < NNODES) {
            float o[8];
#pragma unroll
            for (int j = 0; j < 8; ++j) o[j] = leaky1(leaky1(acc[i][j] + bj[j]));
            float4* op = (float4*)(hout + (size_t)gm * HID + n0);
            op[0] = make_float4(o[0], o[1], o[2], o[3]);
            op[1] = make_float4(o[4], o[5], o[6], o[7]);
            if (zero_aggr) {
                float4* az = (float4*)(aggr + (size_t)gm * HID + n0);
                az[0] = z; az[1] = z;
            }
        }
    }
}

// ---------------- global mean pool (batch sorted) ----------------
__global__ __launch_bounds__(256) void pool_kernel(
    const float* __restrict__ h, const int* __restrict__ batch,
    float* __restrict__ sums, float* __restrict__ cnt)
{
    int c = threadIdx.x & 127;
    int half = threadIdx.x >> 7;
    int base = blockIdx.x * 128 + half * 64;
    if (base >= NNODES) return;
    int end = base + 64; if (end > NNODES) end = NNODES;
    int g = batch[base];
    float acc = 0.0f, k = 0.0f;
    for (int n = base; n < end; ++n) {
        int gn = batch[n];
        if (gn != g) {
            atomicAdd(&sums[g * HID + c], acc);
            if (c == 0) atomicAdd(&cnt[g], k);
            acc = 0.0f; k = 0.0f; g = gn;
        }
        acc += h[(size_t)n * HID + c];
        k += 1.0f;
    }
    atomicAdd(&sums[g * HID + c], acc);
    if (c == 0) atomicAdd(&cnt[g], k);
}

// ---------------- reghead ----------------
__global__ __launch_bounds__(512) void reghead_kernel(
    const float* __restrict__ sums, const float* __restrict__ cnt,
    const float* __restrict__ wr, const float* __restrict__ br,
    const float* __restrict__ we, const float* __restrict__ be,
    float* __restrict__ out)
{
    __shared__ float pool[8 * HID];
    __shared__ float red[8][8];
    int g0 = blockIdx.x * 8;
    for (int i = threadIdx.x; i < 8 * HID; i += 512) {
        int g = g0 + (i >> 7);
        float c = cnt[g]; c = fmaxf(c, 1.0f);
        pool[i] = sums[g * HID + (i & 127)] / c;
    }
    __syncthreads();
    int j = threadIdx.x;
    float p[8];
#pragma unroll
    for (int g = 0; g < 8; ++g) p[g] = 0.0f;
    if (j < RHD) {
        float accs[8];
        float bjv = br[j];
#pragma unroll
        for (int g = 0; g < 8; ++g) accs[g] = bjv;
        const float4* wr4 = (const float4*)(wr + (size_t)j * HID);
        const float4* pool4 = (const float4*)pool;
        for (int k = 0; k < 32; ++k) {
            float4 w = wr4[k];
#pragma unroll
            for (int g = 0; g < 8; ++g) {
                float4 pv = pool4[g * 32 + k];
                accs[g] = fmaf(w.x, pv.x, accs[g]);
                accs[g] = fmaf(w.y, pv.y, accs[g]);
                accs[g] = fmaf(w.z, pv.z, accs[g]);
                accs[g] = fmaf(w.w, pv.w, accs[g]);
            }
        }
        float wej = we[j];
#pragma unroll
        for (int g = 0; g < 8; ++g) p[g] = leaky1(accs[g]) * wej;
    }
    int lane = threadIdx.x & 63, wid = threadIdx.x >> 6;
#pragma unroll
    for (int g = 0; g < 8; ++g) {
        float v = p[g];
        v += __shfl_down(v, 32); v += __shfl_down(v, 16); v += __shfl_down(v, 8);
        v += __shfl_down(v, 4);  v += __shfl_down(v, 2);  v += __shfl_down(v, 1);
        if (lane == 0) red[g][wid] = v;
    }
    __syncthreads();
    if (threadIdx.x < 8) {
        float sv = be[0];
#pragma unroll
        for (int w = 0; w < 8; ++w) sv += red[threadIdx.x][w];
        out[g0 + threadIdx.x] = sv;
    }
}

extern "C" void kernel_launch(void* const* d_in, const int* in_sizes, int n_in,
                              void* d_out, int out_size, void* d_ws, size_t ws_size,
                              hipStream_t stream)
{
    const float* x     = (const float*)d_in[0];
    const int*   ei    = (const int*)d_in[1];
    const int*   batch = (const int*)d_in[2];
    const float* ea    = (const float*)d_in[3];
    const float* ew0   = (const float*)d_in[4];
    const float* eb0   = (const float*)d_in[5];
    const float* w10   = (const float*)d_in[6];
    const float* b10   = (const float*)d_in[7];
    const float* g0v   = (const float*)d_in[8];
    const float* be0   = (const float*)d_in[9];
    const float* w20   = (const float*)d_in[10];
    const float* b20   = (const float*)d_in[11];
    const float* ewS   = (const float*)d_in[12];
    const float* ebS   = (const float*)d_in[13];
    const float* w1S   = (const float*)d_in[14];
    const float* b1S   = (const float*)d_in[15];
    const float* gS    = (const float*)d_in[16];
    const float* beS   = (const float*)d_in[17];
    const float* w2S   = (const float*)d_in[18];
    const float* b2S   = (const float*)d_in[19];
    const float* wr    = (const float*)d_in[20];
    const float* br    = (const float*)d_in[21];
    const float* we    = (const float*)d_in[22];
    const float* be_   = (const float*)d_in[23];

    float* ws   = (float*)d_ws;
    float* h    = ws;
    float* aggr = ws + (size_t)NNODES * HID;
    float* h1   = ws + 2ull * NNODES * HID;
    float* bn   = ws + 3ull * NNODES * HID;
    float* sums = bn + 256;
    float* cnt  = sums + NGRAPH * HID;
    float* out  = (float*)d_out;

    const int NB  = (NNODES + 255) / 256;
    const int NTB = (NNODES + BM - 1) / BM;

    // ---- layer 0 ----
    hipMemsetAsync(aggr, 0, (size_t)NNODES * 2 * sizeof(float), stream);
    edge0_kernel<<<(NEDGES + 255) / 256, 256, 0, stream>>>(x, ei, ea, ew0, eb0, aggr);
    gemm1_l0_kernel<<<NB, 256, 0, stream>>>(x, aggr, w10, b10, h1);
    hipMemsetAsync(bn, 0, 256 * sizeof(float), stream);
    bn_stats_kernel<<<NB, 256, 0, stream>>>(h1, bn);
    gemm2_tiled<<<NTB, 256, 0, stream>>>(h1, bn, g0v, be0, w20, b20, h, aggr, 1);

    // ---- hidden layers ----
    for (int i = 0; i < 3; ++i) {
        edge_kernel<<<NEDGES / 4, 256, 0, stream>>>(h, ei, ea,
            ewS + (size_t)i * HID * 7, ebS + (size_t)i * HID, aggr);
        hipMemsetAsync(bn, 0, 256 * sizeof(float), stream);
        gemm1_tiled<<<NTB, 256, 0, stream>>>(h, aggr,
            w1S + (size_t)i * HID * HID, b1S + (size_t)i * HID, h1, bn);
        gemm2_tiled<<<NTB, 256, 0, stream>>>(h1, bn,
            gS + (size_t)i * HID, beS + (size_t)i * HID,
            w2S + (size_t)i * HID * HID, b2S + (size_t)i * HID, h, aggr, (i < 2) ? 1 : 0);
    }

    // ---- pooling + reghead ----
    hipMemsetAsync(sums, 0, (size_t)(NGRAPH * HID + NGRAPH) * sizeof(float), stream);
    pool_kernel<<<(NNODES + 127) / 128, 256, 0, stream>>>(h, batch, sums, cnt);
    reghead_kernel<<<NGRAPH / 8, 512, 0, stream>>>(sums, cnt, wr, br, we, be_, out);
}

// Round 3
// 1557.718 us; speedup vs baseline: 5.7398x; 5.7398x over previous
//
#include <hip/hip_runtime.h>

#define NNODES 100000
#define NEDGES 600000
#define NGRAPH 64
#define HID 128
#define RHD 500
#define BM 128          // rows per GEMM block
#define GEMM_GRID ((NNODES + BM - 1) / BM)   // 782

__device__ __forceinline__ float leaky1(float x) { return x >= 0.0f ? x : 0.01f * x; }

// ---------------- layer 0: edge message (d=2) ----------------
__global__ __launch_bounds__(256) void edge0_kernel(
    const float* __restrict__ x, const int* __restrict__ ei,
    const float* __restrict__ ea, const float* __restrict__ ew,
    const float* __restrict__ eb, float* __restrict__ aggr2)
{
    int e = blockIdx.x * 256 + threadIdx.x;
    if (e >= NEDGES) return;
    int s = ei[e];
    int d = ei[NEDGES + e];
    float a[7];
#pragma unroll
    for (int k = 0; k < 7; ++k) a[k] = ea[e * 7 + k];
    float e0 = eb[0], e1 = eb[1];
#pragma unroll
    for (int k = 0; k < 7; ++k) { e0 = fmaf(a[k], ew[k], e0); e1 = fmaf(a[k], ew[7 + k], e1); }
    float m0 = fmaxf(x[s * 2 + 0] + e0, 0.0f);
    float m1 = fmaxf(x[s * 2 + 1] + e1, 0.0f);
    atomicAdd(&aggr2[d * 2 + 0], m0);
    atomicAdd(&aggr2[d * 2 + 1], m1);
}

// ---------------- hidden layers: edge message (d=128), one wave per edge ----------------
__global__ __launch_bounds__(256) void edge_kernel(
    const float* __restrict__ xin, const int* __restrict__ ei,
    const float* __restrict__ ea, const float* __restrict__ ew,
    const float* __restrict__ eb, float* __restrict__ aggr)
{
    int lane = threadIdx.x & 63;
    int e = blockIdx.x * 4 + (threadIdx.x >> 6);
    int s = ei[e];
    int d = ei[NEDGES + e];
    float a[7];
#pragma unroll
    for (int k = 0; k < 7; ++k) a[k] = ea[e * 7 + k];
    int j0 = lane, j1 = lane + 64;
    float acc0 = eb[j0], acc1 = eb[j1];
#pragma unroll
    for (int k = 0; k < 7; ++k) {
        acc0 = fmaf(a[k], ew[j0 * 7 + k], acc0);
        acc1 = fmaf(a[k], ew[j1 * 7 + k], acc1);
    }
    float m0 = fmaxf(xin[s * HID + j0] + acc0, 0.0f);
    float m1 = fmaxf(xin[s * HID + j1] + acc1, 0.0f);
    atomicAdd(&aggr[d * HID + j0], m0);
    atomicAdd(&aggr[d * HID + j1], m1);
}

// ---------------- layer 0: GEMM1 (in=2 -> 128), elementwise per node ----------------
__global__ __launch_bounds__(256) void gemm1_l0_kernel(
    const float* __restrict__ x, const float* __restrict__ aggr2,
    const float* __restrict__ w1, const float* __restrict__ b1,
    float* __restrict__ h1)
{
    int n = blockIdx.x * 256 + threadIdx.x;
    if (n >= NNODES) return;
    float x0 = x[n * 2 + 0] + aggr2[n * 2 + 0];
    float x1 = x[n * 2 + 1] + aggr2[n * 2 + 1];
    float4* out4 = (float4*)(h1 + (size_t)n * HID);
    for (int j = 0; j < HID; j += 4) {
        float4 o;
        o.x = fmaf(x1, w1[(j + 0) * 2 + 1], fmaf(x0, w1[(j + 0) * 2 + 0], b1[j + 0]));
        o.y = fmaf(x1, w1[(j + 1) * 2 + 1], fmaf(x0, w1[(j + 1) * 2 + 0], b1[j + 1]));
        o.z = fmaf(x1, w1[(j + 2) * 2 + 1], fmaf(x0, w1[(j + 2) * 2 + 0], b1[j + 2]));
        o.w = fmaf(x1, w1[(j + 3) * 2 + 1], fmaf(x0, w1[(j + 3) * 2 + 0], b1[j + 3]));
        out4[j >> 2] = o;
    }
}

// ---------------- BN partial stats from h1 (layer 0): NON-atomic per-block partials ----------------
__global__ __launch_bounds__(256) void bn_stats_part(
    const float* __restrict__ h1, float* __restrict__ part)
{
    __shared__ float ls[HID], lq[HID];
    int c = threadIdx.x & 127;
    int half = threadIdx.x >> 7;
    int base = blockIdx.x * 256;
    int end = base + 256; if (end > NNODES) end = NNODES;
    float s = 0.0f, q = 0.0f;
    for (int r = base + half; r < end; r += 2) {
        float v = h1[(size_t)r * HID + c];
        s += v;
        q = fmaf(v, v, q);
    }
    if (half) { ls[c] = s; lq[c] = q; }
    __syncthreads();
    if (!half) {
        s += ls[c]; q += lq[c];
        part[(size_t)blockIdx.x * 256 + c] = s;
        part[(size_t)blockIdx.x * 256 + 128 + c] = q;
    }
}

// ---------------- reduce partials -> BN scale/shift (deterministic) ----------------
__global__ __launch_bounds__(64) void bn_finalize(
    const float* __restrict__ part, int nblk,
    const float* __restrict__ gamma, const float* __restrict__ beta,
    float* __restrict__ scsh)
{
    int c = blockIdx.x;           // 0..127
    int lane = threadIdx.x;
    float s = 0.0f, q = 0.0f;
    for (int i = lane; i < nblk; i += 64) {
        s += part[(size_t)i * 256 + c];
        q += part[(size_t)i * 256 + 128 + c];
    }
#pragma unroll
    for (int off = 32; off >= 1; off >>= 1) {
        s += __shfl_down(s, off);
        q += __shfl_down(q, off);
    }
    if (lane == 0) {
        const float invN = 1.0f / (float)NNODES;
        float mu = s * invN;
        float var = fmaf(-mu, mu, q * invN);
        float iv = rsqrtf(var + 1e-5f);
        float sc = gamma[c] * iv;
        scsh[c] = sc;
        scsh[HID + c] = beta[c] - mu * sc;
    }
}

// ---------------- GEMM1 (hidden): h1 = A @ W1^T + b1, A = aggr (= h + messages) ----------------
// W (64KB) in LDS loaded once, xor-swizzled; A streamed per-thread; fused BN partials.
__global__ __launch_bounds__(256) void gemm1_w(
    const float* __restrict__ A, const float* __restrict__ w1,
    const float* __restrict__ b1, float* __restrict__ h1,
    float* __restrict__ part)
{
    __shared__ float4 sW[HID * 32];  // 64KB
    const int t = threadIdx.x;
    for (int l = t; l < HID * 32; l += 256) {
        int row = l >> 5, kk = l & 31;
        sW[row * 32 + (kk ^ ((row >> 3) & 7))] = ((const float4*)w1)[l];
    }
    __syncthreads();

    const int tm = t >> 4, tn = t & 15;
    const int m0 = blockIdx.x * BM + tm * 8;
    const int n0 = tn * 8;
    const int swzb = tn & 7;

    int gm[8];
#pragma unroll
    for (int i = 0; i < 8; ++i) {
        int r = m0 + i;
        gm[i] = r < NNODES ? r : NNODES - 1;
    }
    const float4* A4 = (const float4*)A;

    float acc[8][8];
#pragma unroll
    for (int i = 0; i < 8; ++i)
#pragma unroll
        for (int j = 0; j < 8; ++j) acc[i][j] = 0.0f;

#pragma unroll 2
    for (int kk = 0; kk < 32; ++kk) {
        float4 bfr[8];
#pragma unroll
        for (int j = 0; j < 8; ++j) bfr[j] = sW[(n0 + j) * 32 + (kk ^ swzb)];
        float4 afr[8];
#pragma unroll
        for (int i = 0; i < 8; ++i) afr[i] = A4[(size_t)gm[i] * 32 + kk];
#pragma unroll
        for (int i = 0; i < 8; ++i)
#pragma unroll
            for (int j = 0; j < 8; ++j) {
                acc[i][j] = fmaf(afr[i].x, bfr[j].x, acc[i][j]);
                acc[i][j] = fmaf(afr[i].y, bfr[j].y, acc[i][j]);
                acc[i][j] = fmaf(afr[i].z, bfr[j].z, acc[i][j]);
                acc[i][j] = fmaf(afr[i].w, bfr[j].w, acc[i][j]);
            }
    }

    // epilogue: bias, store, per-block BN partials (no global atomics)
    float bj[8];
#pragma unroll
    for (int j = 0; j < 8; ++j) bj[j] = b1[n0 + j];
    float s[8], q[8];
#pragma unroll
    for (int j = 0; j < 8; ++j) { s[j] = 0.0f; q[j] = 0.0f; }
#pragma unroll
    for (int i = 0; i < 8; ++i) {
        if (m0 + i < NNODES) {
            float o[8];
#pragma unroll
            for (int j = 0; j < 8; ++j) {
                float v = acc[i][j] + bj[j];
                o[j] = v;
                s[j] += v;
                q[j] = fmaf(v, v, q[j]);
            }
            float4* op = (float4*)(h1 + (size_t)(m0 + i) * HID + n0);
            op[0] = make_float4(o[0], o[1], o[2], o[3]);
            op[1] = make_float4(o[4], o[5], o[6], o[7]);
        }
    }
    __syncthreads();                 // done reading sW; reuse as scratch
    float* red = (float*)sW;         // [2][128][16] floats = 16KB
#pragma unroll
    for (int j = 0; j < 8; ++j) {
        red[(n0 + j) * 16 + tm] = s[j];
        red[2048 + (n0 + j) * 16 + tm] = q[j];
    }
    __syncthreads();
    {
        int c = t & 127, wh = t >> 7;
        const float* base = red + wh * 2048 + c * 16;
        float v = 0.0f;
#pragma unroll
        for (int u = 0; u < 16; ++u) v += base[u];
        part[(size_t)blockIdx.x * 256 + wh * 128 + c] = v;
    }
}

// ---------------- GEMM2: hout = leaky(leaky( leaky(BN(h1)) @ W2^T + b2 )); copies into aggr ----------------
__global__ __launch_bounds__(256) void gemm2_w(
    const float* __restrict__ h1, const float* __restrict__ scsh,
    const float* __restrict__ w2, const float* __restrict__ b2,
    float* __restrict__ hout, float* __restrict__ aggr, int copy_aggr)
{
    __shared__ float4 sW[HID * 32];  // 64KB
    const int t = threadIdx.x;
    for (int l = t; l < HID * 32; l += 256) {
        int row = l >> 5, kk = l & 31;
        sW[row * 32 + (kk ^ ((row >> 3) & 7))] = ((const float4*)w2)[l];
    }
    __syncthreads();

    const int tm = t >> 4, tn = t & 15;
    const int m0 = blockIdx.x * BM + tm * 8;
    const int n0 = tn * 8;
    const int swzb = tn & 7;

    int gm[8];
#pragma unroll
    for (int i = 0; i < 8; ++i) {
        int r = m0 + i;
        gm[i] = r < NNODES ? r : NNODES - 1;
    }
    const float4* A4 = (const float4*)h1;
    const float4* sc4 = (const float4*)scsh;
    const float4* sh4 = (const float4*)(scsh + HID);

    float acc[8][8];
#pragma unroll
    for (int i = 0; i < 8; ++i)
#pragma unroll
        for (int j = 0; j < 8; ++j) acc[i][j] = 0.0f;

#pragma unroll 2
    for (int kk = 0; kk < 32; ++kk) {
        float4 bfr[8];
#pragma unroll
        for (int j = 0; j < 8; ++j) bfr[j] = sW[(n0 + j) * 32 + (kk ^ swzb)];
        float4 sc = sc4[kk], sh = sh4[kk];
        float4 afr[8];
#pragma unroll
        for (int i = 0; i < 8; ++i) {
            float4 v = A4[(size_t)gm[i] * 32 + kk];
            afr[i].x = leaky1(fmaf(v.x, sc.x, sh.x));
            afr[i].y = leaky1(fmaf(v.y, sc.y, sh.y));
            afr[i].z = leaky1(fmaf(v.z, sc.z, sh.z));
            afr[i].w = leaky1(fmaf(v.w, sc.w, sh.w));
        }
#pragma unroll
        for (int i = 0; i < 8; ++i)
#pragma unroll
            for (int j = 0; j < 8; ++j) {
                acc[i][j] = fmaf(afr[i].x, bfr[j].x, acc[i][j]);
                acc[i][j] = fmaf(afr[i].y, bfr[j].y, acc[i][j]);
                acc[i][j] = fmaf(afr[i].z, bfr[j].z, acc[i][j]);
                acc[i][j] = fmaf(afr[i].w, bfr[j].w, acc[i][j]);
            }
    }

    float bj[8];
#pragma unroll
    for (int j = 0; j < 8; ++j) bj[j] = b2[n0 + j];
#pragma unroll
    for (int i = 0; i < 8; ++i) {
        if (m0 + i < NNODES) {
            float o[8];
#pragma unroll
            for (int j = 0; j < 8; ++j) o[j] = leaky1(leaky1(acc[i][j] + bj[j]));
            float4 v0 = make_float4(o[0], o[1], o[2], o[3]);
            float4 v1 = make_float4(o[4], o[5], o[6], o[7]);
            float4* op = (float4*)(hout + (size_t)(m0 + i) * HID + n0);
            op[0] = v0; op[1] = v1;
            if (copy_aggr) {
                float4* ap = (float4*)(aggr + (size_t)(m0 + i) * HID + n0);
                ap[0] = v0; ap[1] = v1;
            }
        }
    }
}

// ---------------- global mean pool (batch sorted) ----------------
__global__ __launch_bounds__(256) void pool_kernel(
    const float* __restrict__ h, const int* __restrict__ batch,
    float* __restrict__ sums, float* __restrict__ cnt)
{
    int c = threadIdx.x & 127;
    int half = threadIdx.x >> 7;
    int base = blockIdx.x * 128 + half * 64;
    if (base >= NNODES) return;
    int end = base + 64; if (end > NNODES) end = NNODES;
    int g = batch[base];
    float acc = 0.0f, k = 0.0f;
    for (int n = base; n < end; ++n) {
        int gn = batch[n];
        if (gn != g) {
            atomicAdd(&sums[g * HID + c], acc);
            if (c == 0) atomicAdd(&cnt[g], k);
            acc = 0.0f; k = 0.0f; g = gn;
        }
        acc += h[(size_t)n * HID + c];
        k += 1.0f;
    }
    atomicAdd(&sums[g * HID + c], acc);
    if (c == 0) atomicAdd(&cnt[g], k);
}

// ---------------- reghead ----------------
__global__ __launch_bounds__(512) void reghead_kernel(
    const float* __restrict__ sums, const float* __restrict__ cnt,
    const float* __restrict__ wr, const float* __restrict__ br,
    const float* __restrict__ we, const float* __restrict__ be,
    float* __restrict__ out)
{
    __shared__ float pool[8 * HID];
    __shared__ float red[8][8];
    int g0 = blockIdx.x * 8;
    for (int i = threadIdx.x; i < 8 * HID; i += 512) {
        int g = g0 + (i >> 7);
        float c = cnt[g]; c = fmaxf(c, 1.0f);
        pool[i] = sums[g * HID + (i & 127)] / c;
    }
    __syncthreads();
    int j = threadIdx.x;
    float p[8];
#pragma unroll
    for (int g = 0; g < 8; ++g) p[g] = 0.0f;
    if (j < RHD) {
        float accs[8];
        float bjv = br[j];
#pragma unroll
        for (int g = 0; g < 8; ++g) accs[g] = bjv;
        const float4* wr4 = (const float4*)(wr + (size_t)j * HID);
        const float4* pool4 = (const float4*)pool;
        for (int k = 0; k < 32; ++k) {
            float4 w = wr4[k];
#pragma unroll
            for (int g = 0; g < 8; ++g) {
                float4 pv = pool4[g * 32 + k];
                accs[g] = fmaf(w.x, pv.x, accs[g]);
                accs[g] = fmaf(w.y, pv.y, accs[g]);
                accs[g] = fmaf(w.z, pv.z, accs[g]);
                accs[g] = fmaf(w.w, pv.w, accs[g]);
            }
        }
        float wej = we[j];
#pragma unroll
        for (int g = 0; g < 8; ++g) p[g] = leaky1(accs[g]) * wej;
    }
    int lane = threadIdx.x & 63, wid = threadIdx.x >> 6;
#pragma unroll
    for (int g = 0; g < 8; ++g) {
        float v = p[g];
        v += __shfl_down(v, 32); v += __shfl_down(v, 16); v += __shfl_down(v, 8);
        v += __shfl_down(v, 4);  v += __shfl_down(v, 2);  v += __shfl_down(v, 1);
        if (lane == 0) red[g][wid] = v;
    }
    __syncthreads();
    if (threadIdx.x < 8) {
        float sv = be[0];
#pragma unroll
        for (int w = 0; w < 8; ++w) sv += red[threadIdx.x][w];
        out[g0 + threadIdx.x] = sv;
    }
}

extern "C" void kernel_launch(void* const* d_in, const int* in_sizes, int n_in,
                              void* d_out, int out_size, void* d_ws, size_t ws_size,
                              hipStream_t stream)
{
    const float* x     = (const float*)d_in[0];
    const int*   ei    = (const int*)d_in[1];
    const int*   batch = (const int*)d_in[2];
    const float* ea    = (const float*)d_in[3];
    const float* ew0   = (const float*)d_in[4];
    const float* eb0   = (const float*)d_in[5];
    const float* w10   = (const float*)d_in[6];
    const float* b10   = (const float*)d_in[7];
    const float* g0v   = (const float*)d_in[8];
    const float* be0   = (const float*)d_in[9];
    const float* w20   = (const float*)d_in[10];
    const float* b20   = (const float*)d_in[11];
    const float* ewS   = (const float*)d_in[12];
    const float* ebS   = (const float*)d_in[13];
    const float* w1S   = (const float*)d_in[14];
    const float* b1S   = (const float*)d_in[15];
    const float* gS    = (const float*)d_in[16];
    const float* beS   = (const float*)d_in[17];
    const float* w2S   = (const float*)d_in[18];
    const float* b2S   = (const float*)d_in[19];
    const float* wr    = (const float*)d_in[20];
    const float* br    = (const float*)d_in[21];
    const float* we    = (const float*)d_in[22];
    const float* be_   = (const float*)d_in[23];

    float* ws   = (float*)d_ws;
    float* h    = ws;                                  // N*128
    float* aggr = ws + (size_t)NNODES * HID;           // N*128 (also 2-wide area for layer 0)
    float* h1   = ws + 2ull * NNODES * HID;            // N*128
    float* part = ws + 3ull * NNODES * HID;            // 782*256
    float* scsh = part + (size_t)GEMM_GRID * 256;      // 256
    float* sums = scsh + 256;                          // 64*128
    float* cnt  = sums + NGRAPH * HID;                 // 64
    float* out  = (float*)d_out;

    const int NB = (NNODES + 255) / 256;               // 391

    // ---- layer 0 ----
    hipMemsetAsync(aggr, 0, (size_t)NNODES * 2 * sizeof(float), stream);
    edge0_kernel<<<(NEDGES + 255) / 256, 256, 0, stream>>>(x, ei, ea, ew0, eb0, aggr);
    gemm1_l0_kernel<<<NB, 256, 0, stream>>>(x, aggr, w10, b10, h1);
    bn_stats_part<<<NB, 256, 0, stream>>>(h1, part);
    bn_finalize<<<HID, 64, 0, stream>>>(part, NB, g0v, be0, scsh);
    gemm2_w<<<GEMM_GRID, 256, 0, stream>>>(h1, scsh, w20, b20, h, aggr, 1);

    // ---- hidden layers ----
    for (int i = 0; i < 3; ++i) {
        edge_kernel<<<NEDGES / 4, 256, 0, stream>>>(h, ei, ea,
            ewS + (size_t)i * HID * 7, ebS + (size_t)i * HID, aggr);
        gemm1_w<<<GEMM_GRID, 256, 0, stream>>>(aggr,
            w1S + (size_t)i * HID * HID, b1S + (size_t)i * HID, h1, part);
        bn_finalize<<<HID, 64, 0, stream>>>(part, GEMM_GRID,
            gS + (size_t)i * HID, beS + (size_t)i * HID, scsh);
        gemm2_w<<<GEMM_GRID, 256, 0, stream>>>(h1, scsh,
            w2S + (size_t)i * HID * HID, b2S + (size_t)i * HID, h, aggr, (i < 2) ? 1 : 0);
    }

    // ---- pooling + reghead ----
    hipMemsetAsync(sums, 0, (size_t)(NGRAPH * HID + NGRAPH) * sizeof(float), stream);
    pool_kernel<<<(NNODES + 127) / 128, 256, 0, stream>>>(h, batch, sums, cnt);
    reghead_kernel<<<NGRAPH / 8, 512, 0, stream>>>(sums, cnt, wr, br, we, be_, out);
}

// Round 4
// 1093.201 us; speedup vs baseline: 8.1787x; 1.4249x over previous
//
#include <hip/hip_runtime.h>

#define NNODES 100000
#define NEDGES 600000
#define NGRAPH 64
#define HID 128
#define RHD 500
#define BM 128
#define GEMM_GRID ((NNODES + BM - 1) / BM)   // 782
#define NB ((NNODES + 255) / 256)            // 391
#define EB ((NEDGES + 255) / 256)            // 2344

__device__ __forceinline__ float leaky1(float x) { return x >= 0.0f ? x : 0.01f * x; }

// ================= CSR build (deterministic) =================
__global__ __launch_bounds__(256) void hist_kernel(
    const int* __restrict__ ei, int* __restrict__ deg)
{
    int e = blockIdx.x * 256 + threadIdx.x;
    if (e < NEDGES) atomicAdd(&deg[ei[NEDGES + e]], 1);
}

__global__ __launch_bounds__(256) void scan_blk(
    const int* __restrict__ deg, int* __restrict__ incl, int* __restrict__ bsum)
{
    __shared__ int s[256];
    int t = threadIdx.x;
    int n = blockIdx.x * 256 + t;
    int v = (n < NNODES) ? deg[n] : 0;
    int x = v;
    s[t] = x;
    __syncthreads();
    for (int off = 1; off < 256; off <<= 1) {
        int y = (t >= off) ? s[t - off] : 0;
        __syncthreads();
        x += y; s[t] = x;
        __syncthreads();
    }
    if (n < NNODES) incl[n] = x;
    if (t == 255) bsum[blockIdx.x] = x;
}

__global__ __launch_bounds__(512) void scan_bsum(int* __restrict__ bsum, int nblk)
{
    __shared__ int s[512];
    int t = threadIdx.x;
    int v = (t < nblk) ? bsum[t] : 0;
    int x = v;
    s[t] = x;
    __syncthreads();
    for (int off = 1; off < 512; off <<= 1) {
        int y = (t >= off) ? s[t - off] : 0;
        __syncthreads();
        x += y; s[t] = x;
        __syncthreads();
    }
    if (t < nblk) bsum[t] = x - v;   // exclusive
}

__global__ __launch_bounds__(256) void finalize_rp(
    const int* __restrict__ deg, const int* __restrict__ bsum,
    int* __restrict__ rp, int* __restrict__ cursor)
{
    int n = blockIdx.x * 256 + threadIdx.x;
    if (n >= NNODES) return;
    int ig = rp[n] + bsum[blockIdx.x];   // global inclusive
    int st = ig - deg[n];
    rp[n] = st;
    cursor[n] = st;
    if (n == NNODES - 1) rp[NNODES] = ig;
}

__global__ __launch_bounds__(256) void scatter_kernel(
    const int* __restrict__ ei, int* __restrict__ cursor, int* __restrict__ eid)
{
    int e = blockIdx.x * 256 + threadIdx.x;
    if (e >= NEDGES) return;
    int d = ei[NEDGES + e];
    int pos = atomicAdd(&cursor[d], 1);
    eid[pos] = e;
}

// canonicalize within-segment order -> bitwise-deterministic aggregation
__global__ __launch_bounds__(256) void seg_sort(
    const int* __restrict__ rp, int* __restrict__ eid)
{
    int n = blockIdx.x * 256 + threadIdx.x;
    if (n >= NNODES) return;
    int beg = rp[n], end = rp[n + 1];
    for (int i = beg + 1; i < end; ++i) {
        int key = eid[i];
        int j = i - 1;
        while (j >= beg && eid[j] > key) { eid[j + 1] = eid[j]; --j; }
        eid[j + 1] = key;
    }
}

__global__ __launch_bounds__(256) void permute_kernel(
    const int* __restrict__ eid, const int* __restrict__ ei,
    const float* __restrict__ ea, int* __restrict__ srcp, float* __restrict__ eap)
{
    int p = blockIdx.x * 256 + threadIdx.x;
    if (p >= NEDGES) return;
    int id = eid[p];
    srcp[p] = ei[id];
    const float* s = ea + (size_t)id * 7;
    float* d = eap + (size_t)p * 7;
#pragma unroll
    for (int k = 0; k < 7; ++k) d[k] = s[k];
}

// ================= layer 0 aggregate (d=2): A2[n] = x[n] + sum relu(x[src]+e) =================
__global__ __launch_bounds__(256) void aggregate0_kernel(
    const float* __restrict__ x, const int* __restrict__ rp,
    const int* __restrict__ srcp, const float* __restrict__ eap,
    const float* __restrict__ ew, const float* __restrict__ eb,
    float* __restrict__ aggr2)
{
    int n = blockIdx.x * 256 + threadIdx.x;
    if (n >= NNODES) return;
    float w0[7], w1[7];
#pragma unroll
    for (int k = 0; k < 7; ++k) { w0[k] = ew[k]; w1[k] = ew[7 + k]; }
    float e0b = eb[0], e1b = eb[1];
    float a0 = x[n * 2 + 0], a1 = x[n * 2 + 1];
    int beg = rp[n], end = rp[n + 1];
    for (int e = beg; e < end; ++e) {
        int s = srcp[e];
        const float* ap = eap + (size_t)e * 7;
        float t0 = e0b, t1 = e1b;
#pragma unroll
        for (int k = 0; k < 7; ++k) {
            float av = ap[k];
            t0 = fmaf(av, w0[k], t0);
            t1 = fmaf(av, w1[k], t1);
        }
        a0 += fmaxf(x[s * 2 + 0] + t0, 0.0f);
        a1 += fmaxf(x[s * 2 + 1] + t1, 0.0f);
    }
    aggr2[n * 2 + 0] = a0;
    aggr2[n * 2 + 1] = a1;
}

// ================= hidden aggregate (d=128): one wave per 8 nodes =================
__global__ __launch_bounds__(256) void aggregate_kernel(
    const float* __restrict__ hin, const int* __restrict__ rp,
    const int* __restrict__ srcp, const float* __restrict__ eap,
    const float* __restrict__ ew, const float* __restrict__ eb,
    float* __restrict__ A)
{
    int lane = threadIdx.x & 63;
    int w = threadIdx.x >> 6;
    int nbase = blockIdx.x * 32 + w * 8;
    float ew0[7], ew1[7];
#pragma unroll
    for (int k = 0; k < 7; ++k) {
        ew0[k] = ew[lane * 7 + k];
        ew1[k] = ew[(lane + 64) * 7 + k];
    }
    float eb0v = eb[lane], eb1v = eb[lane + 64];
    for (int n = nbase; n < nbase + 8; ++n) {
        float a0 = hin[(size_t)n * HID + lane];
        float a1 = hin[(size_t)n * HID + 64 + lane];
        int beg = rp[n], end = rp[n + 1];
        for (int e = beg; e < end; ++e) {
            int s = srcp[e];
            const float* ap = eap + (size_t)e * 7;
            float t0 = eb0v, t1 = eb1v;
#pragma unroll
            for (int k = 0; k < 7; ++k) {
                float av = ap[k];
                t0 = fmaf(av, ew0[k], t0);
                t1 = fmaf(av, ew1[k], t1);
            }
            float x0 = hin[(size_t)s * HID + lane];
            float x1 = hin[(size_t)s * HID + 64 + lane];
            a0 += fmaxf(x0 + t0, 0.0f);
            a1 += fmaxf(x1 + t1, 0.0f);
        }
        float* Ap = A + (size_t)n * HID;
        Ap[lane] = a0;
        Ap[64 + lane] = a1;
    }
}

// ================= layer 0 GEMM1 (in=2 -> 128) =================
__global__ __launch_bounds__(256) void gemm1_l0_kernel(
    const float* __restrict__ aggr2,
    const float* __restrict__ w1, const float* __restrict__ b1,
    float* __restrict__ h1)
{
    int n = blockIdx.x * 256 + threadIdx.x;
    if (n >= NNODES) return;
    float x0 = aggr2[n * 2 + 0];
    float x1 = aggr2[n * 2 + 1];
    float4* out4 = (float4*)(h1 + (size_t)n * HID);
    for (int j = 0; j < HID; j += 4) {
        float4 o;
        o.x = fmaf(x1, w1[(j + 0) * 2 + 1], fmaf(x0, w1[(j + 0) * 2 + 0], b1[j + 0]));
        o.y = fmaf(x1, w1[(j + 1) * 2 + 1], fmaf(x0, w1[(j + 1) * 2 + 0], b1[j + 1]));
        o.z = fmaf(x1, w1[(j + 2) * 2 + 1], fmaf(x0, w1[(j + 2) * 2 + 0], b1[j + 2]));
        o.w = fmaf(x1, w1[(j + 3) * 2 + 1], fmaf(x0, w1[(j + 3) * 2 + 0], b1[j + 3]));
        out4[j >> 2] = o;
    }
}

// ================= BN partial stats (layer 0) =================
__global__ __launch_bounds__(256) void bn_stats_part(
    const float* __restrict__ h1, float* __restrict__ part)
{
    __shared__ float ls[HID], lq[HID];
    int c = threadIdx.x & 127;
    int half = threadIdx.x >> 7;
    int base = blockIdx.x * 256;
    int end = base + 256; if (end > NNODES) end = NNODES;
    float s = 0.0f, q = 0.0f;
    for (int r = base + half; r < end; r += 2) {
        float v = h1[(size_t)r * HID + c];
        s += v;
        q = fmaf(v, v, q);
    }
    if (half) { ls[c] = s; lq[c] = q; }
    __syncthreads();
    if (!half) {
        s += ls[c]; q += lq[c];
        part[(size_t)blockIdx.x * 256 + c] = s;
        part[(size_t)blockIdx.x * 256 + 128 + c] = q;
    }
}

// ================= BN finalize -> scale/shift =================
__global__ __launch_bounds__(64) void bn_finalize(
    const float* __restrict__ part, int nblk,
    const float* __restrict__ gamma, const float* __restrict__ beta,
    float* __restrict__ scsh)
{
    int c = blockIdx.x;
    int lane = threadIdx.x;
    float s = 0.0f, q = 0.0f;
    for (int i = lane; i < nblk; i += 64) {
        s += part[(size_t)i * 256 + c];
        q += part[(size_t)i * 256 + 128 + c];
    }
#pragma unroll
    for (int off = 32; off >= 1; off >>= 1) {
        s += __shfl_down(s, off);
        q += __shfl_down(q, off);
    }
    if (lane == 0) {
        const float invN = 1.0f / (float)NNODES;
        float mu = s * invN;
        float var = fmaf(-mu, mu, q * invN);
        float iv = rsqrtf(var + 1e-5f);
        float sc = gamma[c] * iv;
        scsh[c] = sc;
        scsh[HID + c] = beta[c] - mu * sc;
    }
}

// ================= GEMM1 (hidden): h1 = A @ W1^T + b1, IN-PLACE (h1 == A), fused BN partials =================
__global__ __launch_bounds__(256) void gemm1_w(
    const float* __restrict__ A, const float* __restrict__ w1,
    const float* __restrict__ b1, float* __restrict__ h1,
    float* __restrict__ part)
{
    __shared__ float4 sW[HID * 32];  // 64KB
    const int t = threadIdx.x;
    for (int l = t; l < HID * 32; l += 256) {
        int row = l >> 5, kk = l & 31;
        sW[row * 32 + (kk ^ ((row >> 3) & 7))] = ((const float4*)w1)[l];
    }
    __syncthreads();

    const int tm = t >> 4, tn = t & 15;
    const int m0 = blockIdx.x * BM + tm * 8;
    const int n0 = tn * 8;
    const int swzb = tn & 7;

    int gm[8];
#pragma unroll
    for (int i = 0; i < 8; ++i) {
        int r = m0 + i;
        gm[i] = r < NNODES ? r : NNODES - 1;
    }
    const float4* A4 = (const float4*)A;

    float acc[8][8];
#pragma unroll
    for (int i = 0; i < 8; ++i)
#pragma unroll
        for (int j = 0; j < 8; ++j) acc[i][j] = 0.0f;

#pragma unroll 2
    for (int kk = 0; kk < 32; ++kk) {
        float4 bfr[8];
#pragma unroll
        for (int j = 0; j < 8; ++j) bfr[j] = sW[(n0 + j) * 32 + (kk ^ swzb)];
        float4 afr[8];
#pragma unroll
        for (int i = 0; i < 8; ++i) afr[i] = A4[(size_t)gm[i] * 32 + kk];
#pragma unroll
        for (int i = 0; i < 8; ++i)
#pragma unroll
            for (int j = 0; j < 8; ++j) {
                acc[i][j] = fmaf(afr[i].x, bfr[j].x, acc[i][j]);
                acc[i][j] = fmaf(afr[i].y, bfr[j].y, acc[i][j]);
                acc[i][j] = fmaf(afr[i].z, bfr[j].z, acc[i][j]);
                acc[i][j] = fmaf(afr[i].w, bfr[j].w, acc[i][j]);
            }
    }

    __syncthreads();   // all A reads done before in-place stores

    float bj[8];
#pragma unroll
    for (int j = 0; j < 8; ++j) bj[j] = b1[n0 + j];
    float s[8], q[8];
#pragma unroll
    for (int j = 0; j < 8; ++j) { s[j] = 0.0f; q[j] = 0.0f; }
#pragma unroll
    for (int i = 0; i < 8; ++i) {
        if (m0 + i < NNODES) {
            float o[8];
#pragma unroll
            for (int j = 0; j < 8; ++j) {
                float v = acc[i][j] + bj[j];
                o[j] = v;
                s[j] += v;
                q[j] = fmaf(v, v, q[j]);
            }
            float4* op = (float4*)(h1 + (size_t)(m0 + i) * HID + n0);
            op[0] = make_float4(o[0], o[1], o[2], o[3]);
            op[1] = make_float4(o[4], o[5], o[6], o[7]);
        }
    }
    float* red = (float*)sW;
#pragma unroll
    for (int j = 0; j < 8; ++j) {
        red[(n0 + j) * 16 + tm] = s[j];
        red[2048 + (n0 + j) * 16 + tm] = q[j];
    }
    __syncthreads();
    {
        int c = t & 127, wh = t >> 7;
        const float* base = red + wh * 2048 + c * 16;
        float v = 0.0f;
#pragma unroll
        for (int u = 0; u < 16; ++u) v += base[u];
        part[(size_t)blockIdx.x * 256 + wh * 128 + c] = v;
    }
}

// ================= GEMM2: hout = leaky(leaky( leaky(BN(h1)) @ W2^T + b2 )) =================
__global__ __launch_bounds__(256) void gemm2_w(
    const float* __restrict__ h1, const float* __restrict__ scsh,
    const float* __restrict__ w2, const float* __restrict__ b2,
    float* __restrict__ hout)
{
    __shared__ float4 sW[HID * 32];  // 64KB
    const int t = threadIdx.x;
    for (int l = t; l < HID * 32; l += 256) {
        int row = l >> 5, kk = l & 31;
        sW[row * 32 + (kk ^ ((row >> 3) & 7))] = ((const float4*)w2)[l];
    }
    __syncthreads();

    const int tm = t >> 4, tn = t & 15;
    const int m0 = blockIdx.x * BM + tm * 8;
    const int n0 = tn * 8;
    const int swzb = tn & 7;

    int gm[8];
#pragma unroll
    for (int i = 0; i < 8; ++i) {
        int r = m0 + i;
        gm[i] = r < NNODES ? r : NNODES - 1;
    }
    const float4* A4 = (const float4*)h1;
    const float4* sc4 = (const float4*)scsh;
    const float4* sh4 = (const float4*)(scsh + HID);

    float acc[8][8];
#pragma unroll
    for (int i = 0; i < 8; ++i)
#pragma unroll
        for (int j = 0; j < 8; ++j) acc[i][j] = 0.0f;

#pragma unroll 2
    for (int kk = 0; kk < 32; ++kk) {
        float4 bfr[8];
#pragma unroll
        for (int j = 0; j < 8; ++j) bfr[j] = sW[(n0 + j) * 32 + (kk ^ swzb)];
        float4 sc = sc4[kk], sh = sh4[kk];
        float4 afr[8];
#pragma unroll
        for (int i = 0; i < 8; ++i) {
            float4 v = A4[(size_t)gm[i] * 32 + kk];
            afr[i].x = leaky1(fmaf(v.x, sc.x, sh.x));
            afr[i].y = leaky1(fmaf(v.y, sc.y, sh.y));
            afr[i].z = leaky1(fmaf(v.z, sc.z, sh.z));
            afr[i].w = leaky1(fmaf(v.w, sc.w, sh.w));
        }
#pragma unroll
        for (int i = 0; i < 8; ++i)
#pragma unroll
            for (int j = 0; j < 8; ++j) {
                acc[i][j] = fmaf(afr[i].x, bfr[j].x, acc[i][j]);
                acc[i][j] = fmaf(afr[i].y, bfr[j].y, acc[i][j]);
                acc[i][j] = fmaf(afr[i].z, bfr[j].z, acc[i][j]);
                acc[i][j] = fmaf(afr[i].w, bfr[j].w, acc[i][j]);
            }
    }

    float bj[8];
#pragma unroll
    for (int j = 0; j < 8; ++j) bj[j] = b2[n0 + j];
#pragma unroll
    for (int i = 0; i < 8; ++i) {
        if (m0 + i < NNODES) {
            float o[8];
#pragma unroll
            for (int j = 0; j < 8; ++j) o[j] = leaky1(leaky1(acc[i][j] + bj[j]));
            float4* op = (float4*)(hout + (size_t)(m0 + i) * HID + n0);
            op[0] = make_float4(o[0], o[1], o[2], o[3]);
            op[1] = make_float4(o[4], o[5], o[6], o[7]);
        }
    }
}

// ================= global mean pool (batch sorted) =================
__global__ __launch_bounds__(256) void pool_kernel(
    const float* __restrict__ h, const int* __restrict__ batch,
    float* __restrict__ sums, float* __restrict__ cnt)
{
    int c = threadIdx.x & 127;
    int half = threadIdx.x >> 7;
    int base = blockIdx.x * 128 + half * 64;
    if (base >= NNODES) return;
    int end = base + 64; if (end > NNODES) end = NNODES;
    int g = batch[base];
    float acc = 0.0f, k = 0.0f;
    for (int n = base; n < end; ++n) {
        int gn = batch[n];
        if (gn != g) {
            atomicAdd(&sums[g * HID + c], acc);
            if (c == 0) atomicAdd(&cnt[g], k);
            acc = 0.0f; k = 0.0f; g = gn;
        }
        acc += h[(size_t)n * HID + c];
        k += 1.0f;
    }
    atomicAdd(&sums[g * HID + c], acc);
    if (c == 0) atomicAdd(&cnt[g], k);
}

// ================= reghead =================
__global__ __launch_bounds__(512) void reghead_kernel(
    const float* __restrict__ sums, const float* __restrict__ cnt,
    const float* __restrict__ wr, const float* __restrict__ br,
    const float* __restrict__ we, const float* __restrict__ be,
    float* __restrict__ out)
{
    __shared__ float pool[8 * HID];
    __shared__ float red[8][8];
    int g0 = blockIdx.x * 8;
    for (int i = threadIdx.x; i < 8 * HID; i += 512) {
        int g = g0 + (i >> 7);
        float c = cnt[g]; c = fmaxf(c, 1.0f);
        pool[i] = sums[g * HID + (i & 127)] / c;
    }
    __syncthreads();
    int j = threadIdx.x;
    float p[8];
#pragma unroll
    for (int g = 0; g < 8; ++g) p[g] = 0.0f;
    if (j < RHD) {
        float accs[8];
        float bjv = br[j];
#pragma unroll
        for (int g = 0; g < 8; ++g) accs[g] = bjv;
        const float4* wr4 = (const float4*)(wr + (size_t)j * HID);
        const float4* pool4 = (const float4*)pool;
        for (int k = 0; k < 32; ++k) {
            float4 w = wr4[k];
#pragma unroll
            for (int g = 0; g < 8; ++g) {
                float4 pv = pool4[g * 32 + k];
                accs[g] = fmaf(w.x, pv.x, accs[g]);
                accs[g] = fmaf(w.y, pv.y, accs[g]);
                accs[g] = fmaf(w.z, pv.z, accs[g]);
                accs[g] = fmaf(w.w, pv.w, accs[g]);
            }
        }
        float wej = we[j];
#pragma unroll
        for (int g = 0; g < 8; ++g) p[g] = leaky1(accs[g]) * wej;
    }
    int lane = threadIdx.x & 63, wid = threadIdx.x >> 6;
#pragma unroll
    for (int g = 0; g < 8; ++g) {
        float v = p[g];
        v += __shfl_down(v, 32); v += __shfl_down(v, 16); v += __shfl_down(v, 8);
        v += __shfl_down(v, 4);  v += __shfl_down(v, 2);  v += __shfl_down(v, 1);
        if (lane == 0) red[g][wid] = v;
    }
    __syncthreads();
    if (threadIdx.x < 8) {
        float sv = be[0];
#pragma unroll
        for (int w = 0; w < 8; ++w) sv += red[threadIdx.x][w];
        out[g0 + threadIdx.x] = sv;
    }
}

extern "C" void kernel_launch(void* const* d_in, const int* in_sizes, int n_in,
                              void* d_out, int out_size, void* d_ws, size_t ws_size,
                              hipStream_t stream)
{
    const float* x     = (const float*)d_in[0];
    const int*   ei    = (const int*)d_in[1];
    const int*   batch = (const int*)d_in[2];
    const float* ea    = (const float*)d_in[3];
    const float* ew0   = (const float*)d_in[4];
    const float* eb0   = (const float*)d_in[5];
    const float* w10   = (const float*)d_in[6];
    const float* b10   = (const float*)d_in[7];
    const float* g0v   = (const float*)d_in[8];
    const float* be0   = (const float*)d_in[9];
    const float* w20   = (const float*)d_in[10];
    const float* b20   = (const float*)d_in[11];
    const float* ewS   = (const float*)d_in[12];
    const float* ebS   = (const float*)d_in[13];
    const float* w1S   = (const float*)d_in[14];
    const float* b1S   = (const float*)d_in[15];
    const float* gS    = (const float*)d_in[16];
    const float* beS   = (const float*)d_in[17];
    const float* w2S   = (const float*)d_in[18];
    const float* b2S   = (const float*)d_in[19];
    const float* wr    = (const float*)d_in[20];
    const float* br    = (const float*)d_in[21];
    const float* we    = (const float*)d_in[22];
    const float* be_   = (const float*)d_in[23];

    float* ws    = (float*)d_ws;
    float* buf0  = ws;                                   // h
    float* buf1  = buf0 + (size_t)NNODES * HID;          // A / h1 (in-place)
    float* part  = buf1 + (size_t)NNODES * HID;          // GEMM_GRID*256
    float* scsh  = part + (size_t)GEMM_GRID * 256;       // 256
    float* sums  = scsh + 256;                           // 64*128
    float* cnt   = sums + NGRAPH * HID;                  // 64
    float* aggr2 = cnt + NGRAPH;                         // N*2
    float* eap   = aggr2 + (size_t)NNODES * 2;           // E*7
    int*   deg    = (int*)(eap + (size_t)NEDGES * 7);    // N
    int*   cursor = deg + NNODES;                        // N
    int*   bsum   = cursor + NNODES;                     // 512
    int*   rp     = bsum + 512;                          // N+1
    int*   eid    = rp + NNODES + 1;                     // E
    int*   srcp   = eid + NEDGES;                        // E
    float* out   = (float*)d_out;

    // ---- CSR build (deterministic; once per launch) ----
    hipMemsetAsync(deg, 0, (size_t)NNODES * sizeof(int), stream);
    hist_kernel<<<EB, 256, 0, stream>>>(ei, deg);
    scan_blk<<<NB, 256, 0, stream>>>(deg, rp, bsum);
    scan_bsum<<<1, 512, 0, stream>>>(bsum, NB);
    finalize_rp<<<NB, 256, 0, stream>>>(deg, bsum, rp, cursor);
    scatter_kernel<<<EB, 256, 0, stream>>>(ei, cursor, eid);
    seg_sort<<<NB, 256, 0, stream>>>(rp, eid);
    permute_kernel<<<EB, 256, 0, stream>>>(eid, ei, ea, srcp, eap);

    // ---- layer 0 ----
    aggregate0_kernel<<<NB, 256, 0, stream>>>(x, rp, srcp, eap, ew0, eb0, aggr2);
    gemm1_l0_kernel<<<NB, 256, 0, stream>>>(aggr2, w10, b10, buf1);
    bn_stats_part<<<NB, 256, 0, stream>>>(buf1, part);
    bn_finalize<<<HID, 64, 0, stream>>>(part, NB, g0v, be0, scsh);
    gemm2_w<<<GEMM_GRID, 256, 0, stream>>>(buf1, scsh, w20, b20, buf0);

    // ---- hidden layers ----
    for (int i = 0; i < 3; ++i) {
        aggregate_kernel<<<NNODES / 32, 256, 0, stream>>>(buf0, rp, srcp, eap,
            ewS + (size_t)i * HID * 7, ebS + (size_t)i * HID, buf1);
        gemm1_w<<<GEMM_GRID, 256, 0, stream>>>(buf1,
            w1S + (size_t)i * HID * HID, b1S + (size_t)i * HID, buf1, part);
        bn_finalize<<<HID, 64, 0, stream>>>(part, GEMM_GRID,
            gS + (size_t)i * HID, beS + (size_t)i * HID, scsh);
        gemm2_w<<<GEMM_GRID, 256, 0, stream>>>(buf1, scsh,
            w2S + (size_t)i * HID * HID, b2S + (size_t)i * HID, buf0);
    }

    // ---- pooling + reghead ----
    hipMemsetAsync(sums, 0, (size_t)(NGRAPH * HID + NGRAPH) * sizeof(float), stream);
    pool_kernel<<<(NNODES + 127) / 128, 256, 0, stream>>>(buf0, batch, sums, cnt);
    reghead_kernel<<<NGRAPH / 8, 512, 0, stream>>>(sums, cnt, wr, br, we, be_, out);
}